// Round 9
// baseline (573.926 us; speedup 1.0000x reference)
//
#include <hip/hip_runtime.h>

// RGCN, 3 layers. N=100000, E=1.6M, R=16, HID=64.
// Edges sorted by (dst,rel) via two-level LDS-bucketed sort (sparse pass A,
// scan, pass B) -- identical to R8 (best).
// md = src | rel<<20 (one u32/edge).
// Layer kernel R9 EXPERIMENT: gathers via global_load_lds DMA (one
// instruction = 8 edge-rows: 64 lanes x 16B, per-lane global addr from
// ds_bpermute of the md window, wave-uniform LDS dest). Tests whether the
// measured phase-1 floor (53 cy/line/CU = ~16 outstanding x ~850cy) is a
// per-INSTRUCTION tracking limit (-> 8x fewer tracked ops = win) or a
// per-LINE MSHR limit (-> flat). Consume (serial run-length mean, scalar
// metadata) unchanged, reading the LDS stage instead of VGPRs.
// Phase 2 (waves 0-3): out = [H|x] @ Wcat via mfma_f32_16x16x32_bf16.

#define HID   64
#define NREL  16
#define KD    1088          // NREL*HID + HID (root x appended as extra K)
#define NPB   16            // nodes per block (= MFMA M)
#define NPW   2             // nodes per wave (8 waves)
#define LSTR  1096          // LDS row stride (pad 1088 -> 1096)

#define NBKT  1024          // coarse buckets (dst>>7); requires N <= 131072
#define BSH   7             // bucket shift: 128 nodes per bucket
#define BCAP  4096          // sparse per-bucket capacity (mean 2048, sd ~45)
#define FB    2048          // fine bins per bucket: 128 nodes * 16 rels
#define CAPB  4096          // LDS staging capacity in bucket_sort
#define CHA   8192          // edges per coarse-pass block

typedef __attribute__((ext_vector_type(8))) short bf16x8;
typedef __attribute__((ext_vector_type(4))) float f32x4;
typedef unsigned short us16;
typedef unsigned int u32;

__device__ __forceinline__ float b2f(us16 u) {
    union { u32 i; float f; } c; c.i = ((u32)u) << 16; return c.f;
}
__device__ __forceinline__ us16 f2b(float f) {   // round-to-nearest-even
    union { float f; u32 i; } c; c.f = f;
    u32 x = c.i;
    return (us16)((x + 0x7FFFu + ((x >> 16) & 1u)) >> 16);
}

// async 16B/lane global->LDS DMA (lds dest = wave-uniform base + lane*16)
__device__ __forceinline__ void gl_lds16(const us16* g, us16* l) {
    __builtin_amdgcn_global_load_lds(
        (const __attribute__((address_space(1))) void*)g,
        (__attribute__((address_space(3))) void*)l, 16, 0, 0);
}

// ---------- setup: two-level bucket sort by (dst,rel) ----------

// Pass A: place edges into sparse coarse buckets; per-bucket runs are
// contiguous per block, so global writes coalesce.
// packed = src | rel<<17 | dstlow<<21.
__global__ __launch_bounds__(256) void bucket_place(const int* __restrict__ ei,
                                                    const int* __restrict__ et,
                                                    int* __restrict__ cursor_b,
                                                    u32* __restrict__ packed, int E) {
    __shared__ int cnt[NBKT];
    __shared__ int bse[NBKT];
    const int t = threadIdx.x;
    for (int i = t; i < NBKT; i += 256) cnt[i] = 0;
    __syncthreads();
    const int* dstp = ei + E;
    int start = blockIdx.x * CHA, end = min(start + CHA, E);
    for (int e4 = start + t * 4; e4 < end; e4 += 1024) {  // count
        if (e4 + 3 < end) {
            int4 d = *(const int4*)(dstp + e4);
            atomicAdd(&cnt[d.x >> BSH], 1);
            atomicAdd(&cnt[d.y >> BSH], 1);
            atomicAdd(&cnt[d.z >> BSH], 1);
            atomicAdd(&cnt[d.w >> BSH], 1);
        } else {
            for (int e = e4; e < end; ++e) atomicAdd(&cnt[dstp[e] >> BSH], 1);
        }
    }
    __syncthreads();
    for (int i = t; i < NBKT; i += 256) {                 // claim sparse ranges
        int v = cnt[i];
        bse[i] = v ? (i * BCAP + atomicAdd(&cursor_b[i], v)) : 0;
        cnt[i] = 0;
    }
    __syncthreads();
    #define PLACE1(sv, dv, tv)                                            \
        { int b_ = (dv) >> BSH;                                           \
          int r_ = atomicAdd(&cnt[b_], 1);                                \
          packed[bse[b_] + r_] = (u32)(sv) | ((u32)(tv) << 17)            \
                               | ((u32)((dv) & 127) << 21); }
    for (int e4 = start + t * 4; e4 < end; e4 += 1024) {  // place
        if (e4 + 3 < end) {
            int4 sv = *(const int4*)(ei + e4);
            int4 dv = *(const int4*)(dstp + e4);
            int4 tv = *(const int4*)(et + e4);
            PLACE1(sv.x, dv.x, tv.x);
            PLACE1(sv.y, dv.y, tv.y);
            PLACE1(sv.z, dv.z, tv.z);
            PLACE1(sv.w, dv.w, tv.w);
        } else {
            for (int e = e4; e < end; ++e) PLACE1(ei[e], dstp[e], et[e]);
        }
    }
    #undef PLACE1
}

// Exclusive scan of the 1024 post-place bucket counts (single block).
__global__ __launch_bounds__(NBKT) void scan_buckets(const int* __restrict__ cursor_b,
                                                     int* __restrict__ bucket_base,
                                                     int* __restrict__ row_ptr,
                                                     int N, int E) {
    __shared__ int s[NBKT];
    int t = threadIdx.x;
    int v = cursor_b[t];
    s[t] = v; __syncthreads();
    for (int off = 1; off < NBKT; off <<= 1) {
        int tv = (t >= off) ? s[t - off] : 0;
        __syncthreads();
        s[t] += tv;
        __syncthreads();
    }
    int ex = s[t] - v;
    bucket_base[t] = ex;
    if (t == NBKT - 1) bucket_base[NBKT] = ex + v;
    if (t == 0) row_ptr[N] = E;
}

// Pass B: fine sort within each bucket by (dstlow,rel); reads sparse packed,
// emits dense md (coalesced via LDS staging) and row_ptr (from in-LDS scan).
__global__ __launch_bounds__(256) void bucket_sort(const u32* __restrict__ packed,
                                                   const int* __restrict__ bucket_base,
                                                   u32* __restrict__ md,
                                                   int* __restrict__ row_ptr, int N) {
    __shared__ int hist[FB];
    __shared__ int ss[256];
    __shared__ u32 outb[CAPB];
    const int b = blockIdx.x, t = threadIdx.x;
    const int base = bucket_base[b];
    const int cnt = bucket_base[b + 1] - base;
    const u32* pk = packed + (size_t)b * BCAP;

    for (int i = t; i < FB; i += 256) hist[i] = 0;
    __syncthreads();
    for (int i = t; i < cnt; i += 256) {                   // fine histogram
        u32 p = pk[i];
        int f = (int)(((p >> 21) & 127u) * 16u + ((p >> 17) & 15u));
        atomicAdd(&hist[f], 1);
    }
    __syncthreads();
    // exclusive scan of 2048 bins: 8 bins/thread + block scan of per-thread sums
    int loc[8], s = 0;
    #pragma unroll
    for (int j = 0; j < 8; ++j) { loc[j] = hist[t * 8 + j]; s += loc[j]; }
    ss[t] = s; __syncthreads();
    for (int off = 1; off < 256; off <<= 1) {
        int tv = (t >= off) ? ss[t - off] : 0;
        __syncthreads();
        ss[t] += tv;
        __syncthreads();
    }
    int run = ss[t] - s;
    #pragma unroll
    for (int j = 0; j < 8; ++j) { hist[t * 8 + j] = run; run += loc[j]; }
    __syncthreads();
    if (t < 128) {                                         // row_ptr from scan
        int node = b * 128 + t;
        if (node < N) row_ptr[node] = base + hist[t * 16];
    }
    __syncthreads();
    for (int i = t; i < cnt; i += 256) {                   // place into staging
        u32 p = pk[i];
        int f = (int)(((p >> 21) & 127u) * 16u + ((p >> 17) & 15u));
        int pos = atomicAdd(&hist[f], 1);
        u32 v = (p & 0x1FFFFu) | (((p >> 17) & 15u) << 20);
        if (pos < CAPB) outb[pos] = v;
        else            md[base + pos] = v;                // overflow fallback
    }
    __syncthreads();
    for (int i = t; i < cnt && i < CAPB; i += 256)         // coalesced stream-out
        md[base + i] = outb[i];
}

__global__ void convx_kernel(const float* __restrict__ x, us16* __restrict__ xb, int n4) {
    int i = blockIdx.x * 256 + threadIdx.x;    // n4 = N*HID/4
    if (i < n4) {
        float4 v = ((const float4*)x)[i];
        us16* o = xb + i * 4;
        o[0] = f2b(v.x); o[1] = f2b(v.y); o[2] = f2b(v.z); o[3] = f2b(v.w);
    }
}

// WcatT[l][h][k], k = r*64+d for k<1024, else root d = k-1024.  bf16.
__global__ void convw_kernel(const float* __restrict__ W, const float* __restrict__ Wroot,
                             us16* __restrict__ WcatT, int total, int L) {
    int i = blockIdx.x * 256 + threadIdx.x;    // total = L*HID*KD
    if (i < total) {
        int l = i / (HID * KD);
        int rem = i % (HID * KD);
        int h = rem / KD, k = rem % KD;
        float v;
        if (k < NREL * HID) {
            int r = k >> 6, d = k & 63;
            v = W[(((size_t)l * NREL + r) * HID + d) * HID + h];
        } else {
            int d = k - NREL * HID;
            v = Wroot[((size_t)l * HID + d) * HID + h];
        }
        WcatT[i] = f2b(v);
    }
}

// ---------- fused layer kernel ----------

// consume edges [0, wcnt) of a 64-edge metadata window held in p_l.
// Rows are DMA'd 8-per-instruction into the wave's LDS stage (2KB), then
// consumed with the proven serial run-length mean.
__device__ __forceinline__ void proc_window(
        u32 p_l, int wcnt, const us16* __restrict__ x_in, us16* Hrow, us16* stage,
        int lane, float& acc, int& runlen, int& prev, u32& mask)
{
    #pragma unroll 1
    for (int c = 0; c < wcnt; c += 16) {
        int last = wcnt - 1;
        // per-lane global addresses: edge = c + (lane>>3), slice = (lane&7)*16B
        int i0 = c + (lane >> 3);     if (i0 > last) i0 = last;
        int i1 = c + 8 + (lane >> 3); if (i1 > last) i1 = last;
        u32 m0 = (u32)__builtin_amdgcn_ds_bpermute(i0 << 2, (int)p_l);
        u32 m1 = (u32)__builtin_amdgcn_ds_bpermute(i1 << 2, (int)p_l);
        asm volatile("s_waitcnt lgkmcnt(0)" ::: "memory");   // stage reuse + bperm
        const us16* g0 = x_in + (size_t)(m0 & 0xFFFFFu) * HID + (lane & 7) * 8;
        const us16* g1 = x_in + (size_t)(m1 & 0xFFFFFu) * HID + (lane & 7) * 8;
        gl_lds16(g0, stage);           // edges c..c+7   -> stage[0..512)
        gl_lds16(g1, stage + 512);     // edges c+8..c+15 -> stage[512..1024)
        asm volatile("s_waitcnt vmcnt(0)" ::: "memory");
        __builtin_amdgcn_sched_barrier(0);   // consumers must not hoist (rule #18)

        int m = wcnt - c; if (m > 16) m = 16;
        int pe[16]; us16 hv[16];
        #pragma unroll
        for (int j = 0; j < 16; ++j) {
            int idx = c + j; if (idx > last) idx = last;
            pe[j] = __builtin_amdgcn_readlane((int)p_l, idx);    // -> SGPR
            hv[j] = stage[j * 64 + lane];                        // conflict-free
        }
        #pragma unroll
        for (int j = 0; j < 16; ++j) {
            if (j < m) {                          // scalar bound
                int r = (int)(((u32)pe[j]) >> 20);               // SALU
                if (r != prev) {                  // s_cmp + s_cbranch
                    if (prev >= 0) {
                        Hrow[(prev << 6) + lane] =
                            f2b(acc * __builtin_amdgcn_rcpf((float)runlen));
                        mask |= 1u << prev;
                    }
                    prev = r; acc = 0.f; runlen = 0;
                }
                acc += b2f(hv[j]); ++runlen;
            }
        }
    }
}

__global__ __launch_bounds__(512, 6) void layer_kernel(
        const us16* __restrict__ x_in,        // bf16 [N,64]
        const int*  __restrict__ row_ptr,     // [N+1]
        const u32*  __restrict__ md,          // sorted by (dst,rel): src | rel<<20
        const us16* __restrict__ WcatT,       // bf16 [64][1088] this layer
        const float* __restrict__ bias,       // fp32 [64] this layer
        us16* __restrict__ x_out,             // bf16 [N,64]  (if !last)
        float* __restrict__ out_f32,          // fp32 [N,64]  (if last)
        int flags, int N)                     // flags: 1=relu, 2=last
{
    __shared__ us16 H[NPB * LSTR];            // 35072 B
    __shared__ us16 SB[8 * 1024];             // 16384 B DMA stage (2KB/wave)
    const int tid = threadIdx.x, wave = tid >> 6, lane = tid & 63;
    const int node0 = blockIdx.x * NPB;
    const int nodeq = node0 + wave * NPW;
    us16* stage = SB + wave * 1024;

    // ---- phase 1 prologue: metadata windows + root-x rows in flight ----
    int rp[NPW + 1];
    #pragma unroll
    for (int i = 0; i <= NPW; ++i)
        rp[i] = __builtin_amdgcn_readfirstlane(row_ptr[min(nodeq + i, N)]);

    u32 pl[NPW]; us16 xr[NPW];
    #pragma unroll
    for (int q = 0; q < NPW; ++q) {
        int cnt = rp[q + 1] - rp[q];
        pl[q] = (lane < cnt) ? md[rp[q] + lane] : 0;
        xr[q] = (nodeq + q < N) ? x_in[(nodeq + q) * HID + lane] : (us16)0;
    }

    // ---- phase 1: consume node-serial per wave (2 nodes) ----
    #pragma unroll
    for (int q = 0; q < NPW; ++q) {
        int node = nodeq + q;
        if (node >= N) break;
        int start = rp[q], cnt = rp[q + 1] - start;
        us16* Hrow = H + (wave * NPW + q) * LSTR;
        Hrow[NREL * HID + lane] = xr[q];      // root/x columns

        float acc = 0.f;
        int runlen = 0, prev = -1;
        u32 mask = 0;

        proc_window(pl[q], min(cnt, 64), x_in, Hrow, stage, lane,
                    acc, runlen, prev, mask);
        for (int w0 = 64; w0 < cnt; w0 += 64) {            // rare overflow windows
            int wcnt = min(64, cnt - w0);
            u32 p2 = (lane < wcnt) ? md[start + w0 + lane] : 0;
            proc_window(p2, wcnt, x_in, Hrow, stage, lane,
                        acc, runlen, prev, mask);
        }
        if (prev >= 0) {
            Hrow[(prev << 6) + lane] = f2b(acc * __builtin_amdgcn_rcpf((float)runlen));
            mask |= 1u << prev;
        }
        #pragma unroll
        for (int r = 0; r < NREL; ++r)
            if (!(mask & (1u << r))) Hrow[(r << 6) + lane] = 0;
    }
    __syncthreads();

    // ---- phase 2 (waves 0-3): [H|x] @ Wcat ----
    if (wave < 4) {
        const int n16 = lane & 15, quad = lane >> 4;
        f32x4 acc = {0.f, 0.f, 0.f, 0.f};
        const us16* Abase = H + n16 * LSTR + quad * 8;                         // A[m][k]
        const us16* Bbase = WcatT + (size_t)(wave * 16 + n16) * KD + quad * 8; // B[k][n]^T
        #pragma unroll 2
        for (int ks = 0; ks < KD / 32; ++ks) {
            bf16x8 af = *(const bf16x8*)(Abase + ks * 32);
            bf16x8 bf = *(const bf16x8*)(Bbase + ks * 32);
            acc = __builtin_amdgcn_mfma_f32_16x16x32_bf16(af, bf, acc, 0, 0, 0);
        }

        int col = wave * 16 + n16;
        float bv = bias[col];
        #pragma unroll
        for (int ri = 0; ri < 4; ++ri) {
            int nl = quad * 4 + ri, node = node0 + nl;  // C/D: col=lane&15, row=quad*4+ri
            if (node < N) {
                float v = acc[ri] + bv;
                if (flags & 1) v = fmaxf(v, 0.f);
                if (flags & 2) out_f32[node * HID + col] = v;
                else           x_out [node * HID + col] = f2b(v);
            }
        }
    }
}

// ---------- host ----------

extern "C" void kernel_launch(void* const* d_in, const int* in_sizes, int n_in,
                              void* d_out, int out_size, void* d_ws, size_t ws_size,
                              hipStream_t stream) {
    const int*   edge_index = (const int*)  d_in[0];
    const int*   edge_type  = (const int*)  d_in[1];
    const float* node_emb   = (const float*)d_in[2];
    const float* W          = (const float*)d_in[3];
    const float* Wroot      = (const float*)d_in[4];
    const float* bias       = (const float*)d_in[5];
    float* out = (float*)d_out;

    const int E = in_sizes[1];
    const int N = in_sizes[2] / HID;
    const int L = in_sizes[5] / HID;

    char* p = (char*)d_ws;
    size_t off = 0;
    auto carve = [&](size_t bytes) {
        void* q = p + off;
        off = (off + bytes + 255) & ~(size_t)255;
        return q;
    };
    int*   cursor_b    = (int*)  carve((size_t)NBKT * 4);
    int*   bucket_base = (int*)  carve((size_t)(NBKT + 1) * 4);
    int*   row_ptr     = (int*)  carve((size_t)(N + 1) * 4);
    u32*   packed      = (u32*)  carve((size_t)NBKT * BCAP * 4);   // sparse
    u32*   md          = (u32*)  carve((size_t)E * 4);
    us16*  xb0         = (us16*) carve((size_t)N * HID * 2);
    us16*  xb1         = (us16*) carve((size_t)N * HID * 2);
    us16*  WcatT       = (us16*) carve((size_t)L * HID * KD * 2);
    (void)ws_size; (void)n_in; (void)out_size;

    hipMemsetAsync(cursor_b, 0, (size_t)NBKT * 4, stream);

    const int nblkA = (E + CHA - 1) / CHA;
    bucket_place<<<nblkA, 256, 0, stream>>>(edge_index, edge_type, cursor_b, packed, E);
    scan_buckets<<<1, NBKT, 0, stream>>>(cursor_b, bucket_base, row_ptr, N, E);
    bucket_sort<<<(N + 127) / 128, 256, 0, stream>>>(packed, bucket_base, md, row_ptr, N);

    convx_kernel<<<(N * HID / 4 + 255) / 256, 256, 0, stream>>>(node_emb, xb0, N * HID / 4);
    int wtot = L * HID * KD;
    convw_kernel<<<(wtot + 255) / 256, 256, 0, stream>>>(W, Wroot, WcatT, wtot, L);

    int gl = (N + NPB - 1) / NPB;
    us16* xin = xb0;
    us16* xother = xb1;
    for (int l = 0; l < L; ++l) {
        int last = (l == L - 1);
        int flags = (last ? 2 : 1);
        layer_kernel<<<gl, 512, 0, stream>>>(
            xin, row_ptr, md,
            WcatT + (size_t)l * HID * KD, bias + (size_t)l * HID,
            last ? nullptr : xother, last ? out : nullptr,
            flags, N);
        us16* t = xin; xin = xother; xother = t;
    }
}

// Round 10
// 528.682 us; speedup vs baseline: 1.0856x; 1.0856x over previous
//
#include <hip/hip_runtime.h>

// RGCN, 3 layers. N=100000, E=1.6M, R=16, HID=64.
// Edges sorted by (dst,rel) via two-level LDS-bucketed sort:
//   pass A (bucket_place): coarse bucket by dst>>7; per-block LDS histogram
//     + one global cursor claim per (block,bucket); writes into a SPARSE
//     per-bucket region (b*BCAP + offset) -> no pre-count pass needed.
//   scan_buckets: exclusive scan of the 1024 post-place bucket counts.
//   pass B (bucket_sort): one block per bucket (~2048 edges): LDS histogram
//     over 2048 (dstlow,rel) fine keys, in-LDS scan, row_ptr emitted,
//     md compacted sparse->dense, streamed out coalesced via LDS staging.
// md = src | rel<<20 (one u32/edge).
// Layer kernel (R1-best structure; final). R2-R9 falsified every alternative
// limiter: VALU count (R3), software prefetch depth (R4), L1 MSHR via sc0
// bypass (R5), serial dependency chain via MFMA aggregation (R6), wave
// imbalance via work-stealing (R7), per-instruction miss tracking via
// global_load_lds DMA (R9) -- all flat at ~140-155us with line traffic
// pinned at ~83MB. Phase 1 sits at the per-CU random-128B-line service
// ceiling (~16 outstanding line-fills x ~850cy => ~53cy/line/CU). This is
// the structural roofline for this access pattern.
// 512-thread blocks (8 waves), 16 nodes/block, 2 nodes/wave. Phase 1:
// run-length fp32 register accumulation per (node,rel) segment, metadata
// scalarized (readlane -> SGPR, SALU run detection), 16-deep gather
// batches. bf16 flush to LDS H[16][1096]. Phase 2 (waves 0-3):
// out = [H|x] @ Wcat via mfma_f32_16x16x32_bf16 (K=1088).

#define HID   64
#define NREL  16
#define KD    1088          // NREL*HID + HID (root x appended as extra K)
#define NPB   16            // nodes per block (= MFMA M)
#define NPW   2             // nodes per wave (8 waves)
#define LSTR  1096          // LDS row stride (pad 1088 -> 1096)

#define NBKT  1024          // coarse buckets (dst>>7); requires N <= 131072
#define BSH   7             // bucket shift: 128 nodes per bucket
#define BCAP  4096          // sparse per-bucket capacity (mean 2048, sd ~45)
#define FB    2048          // fine bins per bucket: 128 nodes * 16 rels
#define CAPB  4096          // LDS staging capacity in bucket_sort
#define CHA   8192          // edges per coarse-pass block

typedef __attribute__((ext_vector_type(8))) short bf16x8;
typedef __attribute__((ext_vector_type(4))) float f32x4;
typedef unsigned short us16;
typedef unsigned int u32;

__device__ __forceinline__ float b2f(us16 u) {
    union { u32 i; float f; } c; c.i = ((u32)u) << 16; return c.f;
}
__device__ __forceinline__ us16 f2b(float f) {   // round-to-nearest-even
    union { float f; u32 i; } c; c.f = f;
    u32 x = c.i;
    return (us16)((x + 0x7FFFu + ((x >> 16) & 1u)) >> 16);
}

// ---------- setup: two-level bucket sort by (dst,rel) ----------

// Pass A: place edges into sparse coarse buckets; per-bucket runs are
// contiguous per block, so global writes coalesce.
// packed = src | rel<<17 | dstlow<<21.
__global__ __launch_bounds__(256) void bucket_place(const int* __restrict__ ei,
                                                    const int* __restrict__ et,
                                                    int* __restrict__ cursor_b,
                                                    u32* __restrict__ packed, int E) {
    __shared__ int cnt[NBKT];
    __shared__ int bse[NBKT];
    const int t = threadIdx.x;
    for (int i = t; i < NBKT; i += 256) cnt[i] = 0;
    __syncthreads();
    const int* dstp = ei + E;
    int start = blockIdx.x * CHA, end = min(start + CHA, E);
    for (int e4 = start + t * 4; e4 < end; e4 += 1024) {  // count
        if (e4 + 3 < end) {
            int4 d = *(const int4*)(dstp + e4);
            atomicAdd(&cnt[d.x >> BSH], 1);
            atomicAdd(&cnt[d.y >> BSH], 1);
            atomicAdd(&cnt[d.z >> BSH], 1);
            atomicAdd(&cnt[d.w >> BSH], 1);
        } else {
            for (int e = e4; e < end; ++e) atomicAdd(&cnt[dstp[e] >> BSH], 1);
        }
    }
    __syncthreads();
    for (int i = t; i < NBKT; i += 256) {                 // claim sparse ranges
        int v = cnt[i];
        bse[i] = v ? (i * BCAP + atomicAdd(&cursor_b[i], v)) : 0;
        cnt[i] = 0;
    }
    __syncthreads();
    #define PLACE1(sv, dv, tv)                                            \
        { int b_ = (dv) >> BSH;                                           \
          int r_ = atomicAdd(&cnt[b_], 1);                                \
          packed[bse[b_] + r_] = (u32)(sv) | ((u32)(tv) << 17)            \
                               | ((u32)((dv) & 127) << 21); }
    for (int e4 = start + t * 4; e4 < end; e4 += 1024) {  // place
        if (e4 + 3 < end) {
            int4 sv = *(const int4*)(ei + e4);
            int4 dv = *(const int4*)(dstp + e4);
            int4 tv = *(const int4*)(et + e4);
            PLACE1(sv.x, dv.x, tv.x);
            PLACE1(sv.y, dv.y, tv.y);
            PLACE1(sv.z, dv.z, tv.z);
            PLACE1(sv.w, dv.w, tv.w);
        } else {
            for (int e = e4; e < end; ++e) PLACE1(ei[e], dstp[e], et[e]);
        }
    }
    #undef PLACE1
}

// Exclusive scan of the 1024 post-place bucket counts (single block).
__global__ __launch_bounds__(NBKT) void scan_buckets(const int* __restrict__ cursor_b,
                                                     int* __restrict__ bucket_base,
                                                     int* __restrict__ row_ptr,
                                                     int N, int E) {
    __shared__ int s[NBKT];
    int t = threadIdx.x;
    int v = cursor_b[t];
    s[t] = v; __syncthreads();
    for (int off = 1; off < NBKT; off <<= 1) {
        int tv = (t >= off) ? s[t - off] : 0;
        __syncthreads();
        s[t] += tv;
        __syncthreads();
    }
    int ex = s[t] - v;
    bucket_base[t] = ex;
    if (t == NBKT - 1) bucket_base[NBKT] = ex + v;
    if (t == 0) row_ptr[N] = E;
}

// Pass B: fine sort within each bucket by (dstlow,rel); reads sparse packed,
// emits dense md (coalesced via LDS staging) and row_ptr (from in-LDS scan).
__global__ __launch_bounds__(256) void bucket_sort(const u32* __restrict__ packed,
                                                   const int* __restrict__ bucket_base,
                                                   u32* __restrict__ md,
                                                   int* __restrict__ row_ptr, int N) {
    __shared__ int hist[FB];
    __shared__ int ss[256];
    __shared__ u32 outb[CAPB];
    const int b = blockIdx.x, t = threadIdx.x;
    const int base = bucket_base[b];
    const int cnt = bucket_base[b + 1] - base;
    const u32* pk = packed + (size_t)b * BCAP;

    for (int i = t; i < FB; i += 256) hist[i] = 0;
    __syncthreads();
    for (int i = t; i < cnt; i += 256) {                   // fine histogram
        u32 p = pk[i];
        int f = (int)(((p >> 21) & 127u) * 16u + ((p >> 17) & 15u));
        atomicAdd(&hist[f], 1);
    }
    __syncthreads();
    // exclusive scan of 2048 bins: 8 bins/thread + block scan of per-thread sums
    int loc[8], s = 0;
    #pragma unroll
    for (int j = 0; j < 8; ++j) { loc[j] = hist[t * 8 + j]; s += loc[j]; }
    ss[t] = s; __syncthreads();
    for (int off = 1; off < 256; off <<= 1) {
        int tv = (t >= off) ? ss[t - off] : 0;
        __syncthreads();
        ss[t] += tv;
        __syncthreads();
    }
    int run = ss[t] - s;
    #pragma unroll
    for (int j = 0; j < 8; ++j) { hist[t * 8 + j] = run; run += loc[j]; }
    __syncthreads();
    if (t < 128) {                                         // row_ptr from scan
        int node = b * 128 + t;
        if (node < N) row_ptr[node] = base + hist[t * 16];
    }
    __syncthreads();
    for (int i = t; i < cnt; i += 256) {                   // place into staging
        u32 p = pk[i];
        int f = (int)(((p >> 21) & 127u) * 16u + ((p >> 17) & 15u));
        int pos = atomicAdd(&hist[f], 1);
        u32 v = (p & 0x1FFFFu) | (((p >> 17) & 15u) << 20);
        if (pos < CAPB) outb[pos] = v;
        else            md[base + pos] = v;                // overflow fallback
    }
    __syncthreads();
    for (int i = t; i < cnt && i < CAPB; i += 256)         // coalesced stream-out
        md[base + i] = outb[i];
}

__global__ void convx_kernel(const float* __restrict__ x, us16* __restrict__ xb, int n4) {
    int i = blockIdx.x * 256 + threadIdx.x;    // n4 = N*HID/4
    if (i < n4) {
        float4 v = ((const float4*)x)[i];
        us16* o = xb + i * 4;
        o[0] = f2b(v.x); o[1] = f2b(v.y); o[2] = f2b(v.z); o[3] = f2b(v.w);
    }
}

// WcatT[l][h][k], k = r*64+d for k<1024, else root d = k-1024.  bf16.
__global__ void convw_kernel(const float* __restrict__ W, const float* __restrict__ Wroot,
                             us16* __restrict__ WcatT, int total, int L) {
    int i = blockIdx.x * 256 + threadIdx.x;    // total = L*HID*KD
    if (i < total) {
        int l = i / (HID * KD);
        int rem = i % (HID * KD);
        int h = rem / KD, k = rem % KD;
        float v;
        if (k < NREL * HID) {
            int r = k >> 6, d = k & 63;
            v = W[(((size_t)l * NREL + r) * HID + d) * HID + h];
        } else {
            int d = k - NREL * HID;
            v = Wroot[((size_t)l * HID + d) * HID + h];
        }
        WcatT[i] = f2b(v);
    }
}

// ---------- fused layer kernel (R1 structure, best measured) ----------

// consume edges [c0, wcnt) of a 64-edge metadata window held in p_l
__device__ __forceinline__ void proc_window(
        u32 p_l, int c0, int wcnt, const us16* __restrict__ x_in, us16* Hrow, int lane,
        float& acc, int& runlen, int& prev, u32& mask)
{
    #pragma unroll 1
    for (int c = c0; c < wcnt; c += 16) {
        us16 hv[16]; int pe[16];
        #pragma unroll
        for (int j = 0; j < 16; ++j) {           // 16 independent saddr gathers
            int idx = c + j; if (idx >= wcnt) idx = wcnt - 1;
            pe[j] = __builtin_amdgcn_readlane((int)p_l, idx);        // -> SGPR
            hv[j] = x_in[((u32)pe[j] & 0xFFFFFu) * HID + lane];
        }
        int m = wcnt - c; if (m > 16) m = 16;
        #pragma unroll
        for (int j = 0; j < 16; ++j) {
            if (j < m) {                          // scalar bound
                int r = (int)(((u32)pe[j]) >> 20);                   // SALU
                if (r != prev) {                  // s_cmp + s_cbranch
                    if (prev >= 0) {
                        Hrow[(prev << 6) + lane] =
                            f2b(acc * __builtin_amdgcn_rcpf((float)runlen));
                        mask |= 1u << prev;
                    }
                    prev = r; acc = 0.f; runlen = 0;
                }
                acc += b2f(hv[j]); ++runlen;
            }
        }
    }
}

__global__ __launch_bounds__(512, 8) void layer_kernel(
        const us16* __restrict__ x_in,        // bf16 [N,64]
        const int*  __restrict__ row_ptr,     // [N+1]
        const u32*  __restrict__ md,          // sorted by (dst,rel): src | rel<<20
        const us16* __restrict__ WcatT,       // bf16 [64][1088] this layer
        const float* __restrict__ bias,       // fp32 [64] this layer
        us16* __restrict__ x_out,             // bf16 [N,64]  (if !last)
        float* __restrict__ out_f32,          // fp32 [N,64]  (if last)
        int flags, int N)                     // flags: 1=relu, 2=last
{
    __shared__ us16 H[NPB * LSTR];            // 35072 B -> 4 blocks/CU (32 waves)
    const int tid = threadIdx.x, wave = tid >> 6, lane = tid & 63;
    const int node0 = blockIdx.x * NPB;
    const int nodeq = node0 + wave * NPW;

    // ---- phase 1 prologue: metadata windows + root-x rows in flight ----
    int rp[NPW + 1];
    #pragma unroll
    for (int i = 0; i <= NPW; ++i)
        rp[i] = __builtin_amdgcn_readfirstlane(row_ptr[min(nodeq + i, N)]);

    u32 pl[NPW]; us16 xr[NPW];
    #pragma unroll
    for (int q = 0; q < NPW; ++q) {
        int cnt = rp[q + 1] - rp[q];
        pl[q] = (lane < cnt) ? md[rp[q] + lane] : 0;
        xr[q] = (nodeq + q < N) ? x_in[(nodeq + q) * HID + lane] : (us16)0;
    }

    // ---- phase 1: consume node-serial per wave (2 nodes) ----
    #pragma unroll
    for (int q = 0; q < NPW; ++q) {
        int node = nodeq + q;
        if (node >= N) break;
        int start = rp[q], cnt = rp[q + 1] - start;
        us16* Hrow = H + (wave * NPW + q) * LSTR;
        Hrow[NREL * HID + lane] = xr[q];      // root/x columns

        float acc = 0.f;
        int runlen = 0, prev = -1;
        u32 mask = 0;

        proc_window(pl[q], 0, min(cnt, 64), x_in, Hrow, lane, acc, runlen, prev, mask);
        for (int w0 = 64; w0 < cnt; w0 += 64) {            // rare overflow windows
            int wcnt = min(64, cnt - w0);
            u32 p2 = (lane < wcnt) ? md[start + w0 + lane] : 0;
            proc_window(p2, 0, wcnt, x_in, Hrow, lane, acc, runlen, prev, mask);
        }
        if (prev >= 0) {
            Hrow[(prev << 6) + lane] = f2b(acc * __builtin_amdgcn_rcpf((float)runlen));
            mask |= 1u << prev;
        }
        #pragma unroll
        for (int r = 0; r < NREL; ++r)
            if (!(mask & (1u << r))) Hrow[(r << 6) + lane] = 0;
    }
    __syncthreads();

    // ---- phase 2 (waves 0-3): [H|x] @ Wcat ----
    if (wave < 4) {
        const int n16 = lane & 15, quad = lane >> 4;
        f32x4 acc = {0.f, 0.f, 0.f, 0.f};
        const us16* Abase = H + n16 * LSTR + quad * 8;                         // A[m][k]
        const us16* Bbase = WcatT + (size_t)(wave * 16 + n16) * KD + quad * 8; // B[k][n]^T
        #pragma unroll 2
        for (int ks = 0; ks < KD / 32; ++ks) {
            bf16x8 af = *(const bf16x8*)(Abase + ks * 32);
            bf16x8 bf = *(const bf16x8*)(Bbase + ks * 32);
            acc = __builtin_amdgcn_mfma_f32_16x16x32_bf16(af, bf, acc, 0, 0, 0);
        }

        int col = wave * 16 + n16;
        float bv = bias[col];
        #pragma unroll
        for (int ri = 0; ri < 4; ++ri) {
            int nl = quad * 4 + ri, node = node0 + nl;  // C/D: col=lane&15, row=quad*4+ri
            if (node < N) {
                float v = acc[ri] + bv;
                if (flags & 1) v = fmaxf(v, 0.f);
                if (flags & 2) out_f32[node * HID + col] = v;
                else           x_out [node * HID + col] = f2b(v);
            }
        }
    }
}

// ---------- host ----------

extern "C" void kernel_launch(void* const* d_in, const int* in_sizes, int n_in,
                              void* d_out, int out_size, void* d_ws, size_t ws_size,
                              hipStream_t stream) {
    const int*   edge_index = (const int*)  d_in[0];
    const int*   edge_type  = (const int*)  d_in[1];
    const float* node_emb   = (const float*)d_in[2];
    const float* W          = (const float*)d_in[3];
    const float* Wroot      = (const float*)d_in[4];
    const float* bias       = (const float*)d_in[5];
    float* out = (float*)d_out;

    const int E = in_sizes[1];
    const int N = in_sizes[2] / HID;
    const int L = in_sizes[5] / HID;

    char* p = (char*)d_ws;
    size_t off = 0;
    auto carve = [&](size_t bytes) {
        void* q = p + off;
        off = (off + bytes + 255) & ~(size_t)255;
        return q;
    };
    int*   cursor_b    = (int*)  carve((size_t)NBKT * 4);
    int*   bucket_base = (int*)  carve((size_t)(NBKT + 1) * 4);
    int*   row_ptr     = (int*)  carve((size_t)(N + 1) * 4);
    u32*   packed      = (u32*)  carve((size_t)NBKT * BCAP * 4);   // sparse
    u32*   md          = (u32*)  carve((size_t)E * 4);
    us16*  xb0         = (us16*) carve((size_t)N * HID * 2);
    us16*  xb1         = (us16*) carve((size_t)N * HID * 2);
    us16*  WcatT       = (us16*) carve((size_t)L * HID * KD * 2);
    (void)ws_size; (void)n_in; (void)out_size;

    hipMemsetAsync(cursor_b, 0, (size_t)NBKT * 4, stream);

    const int nblkA = (E + CHA - 1) / CHA;
    bucket_place<<<nblkA, 256, 0, stream>>>(edge_index, edge_type, cursor_b, packed, E);
    scan_buckets<<<1, NBKT, 0, stream>>>(cursor_b, bucket_base, row_ptr, N, E);
    bucket_sort<<<(N + 127) / 128, 256, 0, stream>>>(packed, bucket_base, md, row_ptr, N);

    convx_kernel<<<(N * HID / 4 + 255) / 256, 256, 0, stream>>>(node_emb, xb0, N * HID / 4);
    int wtot = L * HID * KD;
    convw_kernel<<<(wtot + 255) / 256, 256, 0, stream>>>(W, Wroot, WcatT, wtot, L);

    int gl = (N + NPB - 1) / NPB;
    us16* xin = xb0;
    us16* xother = xb1;
    for (int l = 0; l < L; ++l) {
        int last = (l == L - 1);
        int flags = (last ? 2 : 1);
        layer_kernel<<<gl, 512, 0, stream>>>(
            xin, row_ptr, md,
            WcatT + (size_t)l * HID * KD, bias + (size_t)l * HID,
            last ? nullptr : xother, last ? out : nullptr,
            flags, N);
        us16* t = xin; xin = xother; xother = t;
    }
}